// Round 6
// baseline (88.700 us; speedup 1.0000x reference)
//
#include <hip/hip_runtime.h>
#include <hip/hip_bf16.h>
#include <stdint.h>

#define NFEATS 128

typedef __attribute__((ext_vector_type(8))) short bf16x8;
typedef __attribute__((ext_vector_type(4))) float f32x4;
typedef __attribute__((ext_vector_type(4))) short short4v;

__device__ inline short f2bf(float f) {
    union { float f; unsigned u; } c; c.f = f;
    unsigned u = c.u;
    return (short)((u + 0x7FFFu + ((u >> 16) & 1u)) >> 16);  // RNE
}
__device__ inline float bf2f(short v) {
    union { unsigned u; float f; } c;
    c.u = ((unsigned)(unsigned short)v) << 16;
    return c.f;
}

// Fused precompute for both tables (blockIdx.y selects):
//   y == 0: A[n,j] = sum_k item[n,k] * W1[j,   k] + b1[j]
//   y == 1: B[n,j] = sum_k user[n,k] * W1[j,128+k]
// SWAPPED-MFMA variant: compute D = W_blk · X^T so each lane holds
// node = lane&15 and 4 CONSECUTIVE output cols (q*4+rr) -> 8B packed stores
// (4 dwordx2 per lane per tile) instead of 16 scalar 2B stores.
__global__ __launch_bounds__(512, 4) void precompute_kernel(
    const float* __restrict__ item, const float* __restrict__ user,
    const float* __restrict__ W1, const float* __restrict__ b1,
    short* __restrict__ A, short* __restrict__ B, int n_nodes)
{
    __shared__ __align__(1024) uint8_t lds[34816 + 32768];  // [W/buf0 | buf1]

    const int which = blockIdx.y;
    const float* __restrict__ X = which ? user : item;
    short* __restrict__ Out = which ? B : A;
    const int k_off4 = which ? 32 : 0;   // in float4 units (128 floats)

    const int tid = threadIdx.x;
    const int w = tid >> 6, lane = tid & 63;
    const int r16 = lane & 15, q = lane >> 4;     // q in 0..3
    const int rowgrp = w >> 1, colhalf = w & 1;

    // ---- stage W (fp32 -> bf16) into padded LDS ----
    {
        short (*Wl)[136] = (short (*)[136])lds;
        const float4* W4 = (const float4*)W1;     // row stride 64 float4
        for (int i = tid; i < 128 * 32; i += 512) {
            int j = i >> 5, c = i & 31;
            float4 wv = W4[j * 64 + k_off4 + c];
            short4v p;
            p[0] = f2bf(wv.x); p[1] = f2bf(wv.y); p[2] = f2bf(wv.z); p[3] = f2bf(wv.w);
            *(short4v*)&Wl[j][c * 4] = p;
        }
    }
    __syncthreads();

    // ---- lift this wave's W fragments + bias into registers ----
    // wfrag[n] holds W[col = colhalf*64 + n*16 + r16][k] — used as MFMA *A*
    // operand (row = r16), afrag used as *B* operand (col = r16): D = W·X^T.
    bf16x8 wfrag[4][4];
    f32x4 bias4[4];   // bias for cols j = colhalf*64 + n*16 + q*4 + rr
    {
        short (*Wl)[136] = (short (*)[136])lds;
#pragma unroll
        for (int n = 0; n < 4; ++n) {
            int col = colhalf * 64 + n * 16 + r16;
#pragma unroll
            for (int kk = 0; kk < 4; ++kk)
                wfrag[n][kk] = *(const bf16x8*)&Wl[col][kk * 32 + q * 8];
            if (which) {
                f32x4 z = {0.f, 0.f, 0.f, 0.f};
                bias4[n] = z;
            } else {
                float4 bv = *(const float4*)&b1[colhalf * 64 + n * 16 + q * 4];
                f32x4 b = {bv.x, bv.y, bv.z, bv.w};
                bias4[n] = b;
            }
        }
    }
    __syncthreads();   // W region now reusable as X buffer 0

    const int n_tiles = (n_nodes + 63) >> 6;

    // Stage one 64-row tile into buffer `buf` (linear LDS, swizzled global src).
    // Storage rule: X[row r][16B-chunk c] lives at LDS r*512 + (c^(r&7))*16.
    auto stage = [&](int buf, int t) {
        uint8_t* base = lds + buf * 34816;
#pragma unroll
        for (int i = 0; i < 4; ++i) {
            int o = (w << 12) + (i << 10) + (lane << 4);   // linear byte off in tile
            int r = o >> 9;
            int c_lds = (o >> 4) & 31;
            int node = (t << 6) + r;
            if (node >= n_nodes) node = n_nodes - 1;       // clamp (stores predicated)
            const uint8_t* gp = (const uint8_t*)X + (size_t)node * 512
                              + (size_t)(((c_lds ^ (r & 7)) << 4));
            auto g1 = (const __attribute__((address_space(1))) uint32_t*)gp;
            auto l3 = (__attribute__((address_space(3))) uint32_t*)(base + (w << 12) + (i << 10));
            __builtin_amdgcn_global_load_lds(g1, l3, 16, 0, 0);
        }
    };

    int t = blockIdx.x;
    if (t < n_tiles) stage(0, t);
    int cur = 0;

    for (; t < n_tiles; t += gridDim.x) {
        __syncthreads();                         // drains vmcnt -> buf[cur] ready
        int tn = t + gridDim.x;
        if (tn < n_tiles) stage(cur ^ 1, tn);    // async prefetch next tile

        // ---- X fragments from buf[cur] (swizzled ds_read_b128) ----
        const uint8_t* base = lds + cur * 34816;
        const int r = rowgrp * 16 + r16;
        const uint8_t* rowp = base + r * 512;
        const int s = r & 7;
        bf16x8 afrag[4];
#pragma unroll
        for (int kk = 0; kk < 4; ++kk) {
            int c0 = kk * 8 + q * 2;
            float4 v0 = *(const float4*)(rowp + ((c0 ^ s) << 4));
            float4 v1 = *(const float4*)(rowp + (((c0 + 1) ^ s) << 4));
            bf16x8 f;
            f[0] = f2bf(v0.x); f[1] = f2bf(v0.y); f[2] = f2bf(v0.z); f[3] = f2bf(v0.w);
            f[4] = f2bf(v1.x); f[5] = f2bf(v1.y); f[6] = f2bf(v1.z); f[7] = f2bf(v1.w);
            afrag[kk] = f;
        }

        // ---- swapped MFMA: D[j][node] = sum_k W[j][k] * X[node][k] ----
        f32x4 acc[4];
#pragma unroll
        for (int n = 0; n < 4; ++n) acc[n] = bias4[n];
#pragma unroll
        for (int n = 0; n < 4; ++n)
#pragma unroll
            for (int kk = 0; kk < 4; ++kk)
                acc[n] = __builtin_amdgcn_mfma_f32_16x16x32_bf16(wfrag[n][kk], afrag[kk], acc[n], 0, 0, 0);

        // ---- packed coalesced store: lane = node r16, cols q*4..q*4+3 ----
        const int node = (t << 6) + rowgrp * 16 + r16;
        if (node < n_nodes) {
            short* orow = Out + (size_t)node * NFEATS + colhalf * 64 + q * 4;
#pragma unroll
            for (int n = 0; n < 4; ++n) {
                uint32_t lo = (uint32_t)(uint16_t)f2bf(acc[n][0])
                            | ((uint32_t)(uint16_t)f2bf(acc[n][1]) << 16);
                uint32_t hi = (uint32_t)(uint16_t)f2bf(acc[n][2])
                            | ((uint32_t)(uint16_t)f2bf(acc[n][3]) << 16);
                uint2 pk = {lo, hi};
                *(uint2*)(orow + n * 16) = pk;
            }
        }
        cur ^= 1;
    }
}

// Edge stage: score[e] = dot(relu(A[src[e]] + B[dst[e]]), w2) + b2
// One quarter-wave (16 lanes) per edge, 2 edges in flight per iteration.
__global__ __launch_bounds__(256) void edge_kernel(
    const short* __restrict__ A, const short* __restrict__ B,
    const int* __restrict__ src, const int* __restrict__ dst,
    const float* __restrict__ W2, const float* __restrict__ b2,
    float* __restrict__ out, int n_edges)
{
    const int t = blockIdx.x * 256 + threadIdx.x;
    const int lane16 = threadIdx.x & 15;

    float w2v[8];
#pragma unroll
    for (int j = 0; j < 8; ++j) w2v[j] = W2[lane16 * 8 + j];
    const float b2v = b2[0];

    const int qw = t >> 4;
    const int nqw = (gridDim.x * 256) >> 4;

    for (int e0 = qw; e0 < n_edges; e0 += 2 * nqw) {
        const int e1 = e0 + nqw;
        const bool has1 = e1 < n_edges;

        int s0 = src[e0], d0 = dst[e0];
        int s1 = has1 ? src[e1] : s0;
        int d1 = has1 ? dst[e1] : d0;

        bf16x8 av0 = *(const bf16x8*)(A + (size_t)s0 * NFEATS + lane16 * 8);
        bf16x8 bv0 = *(const bf16x8*)(B + (size_t)d0 * NFEATS + lane16 * 8);
        bf16x8 av1 = *(const bf16x8*)(A + (size_t)s1 * NFEATS + lane16 * 8);
        bf16x8 bv1 = *(const bf16x8*)(B + (size_t)d1 * NFEATS + lane16 * 8);

        float acc0 = 0.f, acc1 = 0.f;
#pragma unroll
        for (int j = 0; j < 8; ++j) {
            float h0 = bf2f(av0[j]) + bf2f(bv0[j]);
            h0 = fmaxf(h0, 0.f);
            acc0 = fmaf(h0, w2v[j], acc0);
            float h1 = bf2f(av1[j]) + bf2f(bv1[j]);
            h1 = fmaxf(h1, 0.f);
            acc1 = fmaf(h1, w2v[j], acc1);
        }
#pragma unroll
        for (int sh = 1; sh <= 8; sh <<= 1) {
            acc0 += __shfl_xor(acc0, sh);
            acc1 += __shfl_xor(acc1, sh);
        }
        if (lane16 == 0) {
            out[e0] = acc0 + b2v;
            if (has1) out[e1] = acc1 + b2v;
        }
    }
}

extern "C" void kernel_launch(void* const* d_in, const int* in_sizes, int n_in,
                              void* d_out, int out_size, void* d_ws, size_t ws_size,
                              hipStream_t stream) {
    const float* item = (const float*)d_in[0];
    const float* user = (const float*)d_in[1];
    const float* W1   = (const float*)d_in[2];
    const float* b1   = (const float*)d_in[3];
    const float* W2   = (const float*)d_in[4];
    const float* b2   = (const float*)d_in[5];
    const int*   src  = (const int*)d_in[6];
    const int*   dst  = (const int*)d_in[7];
    float* out = (float*)d_out;

    const int n_nodes = in_sizes[0] / NFEATS;
    const int n_edges = in_sizes[6];

    short* A = (short*)d_ws;                         // [n_nodes][128] bf16
    short* B = A + (size_t)n_nodes * NFEATS;         // [n_nodes][128] bf16

    dim3 grid(256, 2);                               // 512 blocks = 2/CU resident
    precompute_kernel<<<grid, 512, 0, stream>>>(item, user, W1, b1, A, B, n_nodes);

    edge_kernel<<<2048, 256, 0, stream>>>(A, B, src, dst, W2, b2, out, n_edges);
}